// Round 12
// baseline (415.354 us; speedup 1.0000x reference)
//
#include <hip/hip_runtime.h>
#include <hip/hip_bf16.h>
#include <cstdint>
#include <cstddef>

#define NN 50000
#define RR 4
#define EE 400000
#define TE (RR*EE)
#define HR2 25000        // hist bins per range (2 ranges * 25000 = 50000)
#define RN (RR*NN)       // 200000
#define NSEG (NN*RR)     // 200000 (d-major, r-minor segments)
#define SCB2 782         // ceil(NSEG/256)
#define NBK 512          // dst buckets for the partition
#define BKSZ 98          // nodes per bucket (512*98 >= 50000)
#define CHA 4000         // edges per phase-A block (100 chunks/relation)
#define MAXSPAN 4608     // LDS image capacity (avg span ~3136)
#define XBLK 6250        // cvt_all blocks for x (50000*32/256)

using frag_ab = __attribute__((ext_vector_type(8))) short;   // 8 bf16 (4 VGPRs)
using frag_cd = __attribute__((ext_vector_type(4))) float;   // 4 fp32

static __device__ __forceinline__ unsigned short f2bf(float f) {
    union { float f; unsigned u; } v; v.f = f;
    unsigned r = (v.u + 0x7FFF + ((v.u >> 16) & 1)) >> 16;   // RNE
    return (unsigned short)r;
}
static __device__ __forceinline__ unsigned pack2(float lo, float hi) {
    return (unsigned)f2bf(lo) | ((unsigned)f2bf(hi) << 16);
}
static __device__ __forceinline__ float blo(unsigned u) { return __uint_as_float(u << 16); }
static __device__ __forceinline__ float bhi(unsigned u) { return __uint_as_float(u & 0xFFFF0000u); }

// ---------------- degree histograms: 2-range split, packed 16-bit LDS bins ----------
// 64 blocks: combo = bid>>3 (r*2+side), range = (bid>>2)&1, chunk = bid&3
__global__ __launch_bounds__(1024) void k_hist(const int* __restrict__ src,
                                               const int* __restrict__ dst,
                                               int* __restrict__ cnt_srcQ,
                                               int* __restrict__ cnt_dstQ) {
    __shared__ unsigned bins[HR2 / 2];   // 12500 uints = 50 KB
    int combo = blockIdx.x >> 3;
    int range = (blockIdx.x >> 2) & 1;
    int qc    = blockIdx.x & 3;
    int r = combo >> 1;
    int side = combo & 1;
    const int* arr = (side == 0 ? src : dst) + (size_t)r * EE + (size_t)qc * (EE / 4);
    int lo = range * HR2;
    for (int i = threadIdx.x; i < HR2 / 2; i += 1024) bins[i] = 0;
    __syncthreads();
    const int4* a4 = (const int4*)arr;
    for (int i = threadIdx.x; i < EE / 16; i += 1024) {
        int4 v = a4[i];
        int t;
        t = v.x - lo; if ((unsigned)t < (unsigned)HR2) atomicAdd(&bins[t >> 1], 1u << ((t & 1) * 16));
        t = v.y - lo; if ((unsigned)t < (unsigned)HR2) atomicAdd(&bins[t >> 1], 1u << ((t & 1) * 16));
        t = v.z - lo; if ((unsigned)t < (unsigned)HR2) atomicAdd(&bins[t >> 1], 1u << ((t & 1) * 16));
        t = v.w - lo; if ((unsigned)t < (unsigned)HR2) atomicAdd(&bins[t >> 1], 1u << ((t & 1) * 16));
    }
    __syncthreads();
    int* outp = (side == 0 ? cnt_srcQ : cnt_dstQ) + (size_t)qc * RN + (size_t)r * NN + lo;
    for (int i = threadIdx.x; i < HR2 / 2; i += 1024) {
        unsigned b = bins[i];
        outp[2 * i]     = (int)(b & 0xFFFFu);
        outp[2 * i + 1] = (int)(b >> 16);
    }
}

// sum quarters -> norms ([r*NN+d]) + counts in [d*4+r] layout for the scan
__global__ __launch_bounds__(256) void k_sum_norms(const int* __restrict__ cnt_srcQ,
                                                   const int* __restrict__ cnt_dstQ,
                                                   float* __restrict__ nsrc,
                                                   float* __restrict__ ndst,
                                                   int* __restrict__ cntd2) {
    int i = blockIdx.x * 256 + threadIdx.x;
    if (i >= RN) return;
    int ss = cnt_srcQ[i] + cnt_srcQ[RN + i] + cnt_srcQ[2 * RN + i] + cnt_srcQ[3 * RN + i];
    int ds = cnt_dstQ[i] + cnt_dstQ[RN + i] + cnt_dstQ[2 * RN + i] + cnt_dstQ[3 * RN + i];
    nsrc[i] = 1.0f / sqrtf(fmaxf((float)ss, 1.0f));
    ndst[i] = 1.0f / sqrtf(fmaxf((float)ds, 1.0f));
    int r = i / NN, d = i - r * NN;
    cntd2[d * 4 + r] = ds;
}

// ---------------- 3-phase parallel scan over 200K (d,r) segment counts ----------------
__global__ __launch_bounds__(256) void k_partial(const int* __restrict__ cntd2,
                                                 int* __restrict__ part) {
    __shared__ int s[256];
    int t = threadIdx.x;
    int f = blockIdx.x * 256 + t;
    int v = (f < NSEG) ? cntd2[f] : 0;
    s[t] = v;
    __syncthreads();
    for (int off = 128; off > 0; off >>= 1) {
        if (t < off) s[t] += s[t + off];
        __syncthreads();
    }
    if (t == 0) part[blockIdx.x] = s[0];
}

__global__ __launch_bounds__(1024) void k_scan_small(const int* __restrict__ part,
                                                     int* __restrict__ offs) {
    __shared__ int s[1024];
    int t = threadIdx.x;
    s[t] = (t < SCB2) ? part[t] : 0;
    __syncthreads();
    for (int off = 1; off < 1024; off <<= 1) {
        int v = (t >= off) ? s[t - off] : 0;
        __syncthreads();
        s[t] += v;
        __syncthreads();
    }
    if (t < SCB2) offs[t] = (t == 0) ? 0 : s[t - 1];
}

// emits rp2 AND the bucket staging cursors (k_initg folded in)
__global__ __launch_bounds__(256) void k_emit(const int* __restrict__ cntd2,
                                              const int* __restrict__ offs,
                                              int* __restrict__ rp2,
                                              int* __restrict__ gcur) {
    __shared__ int s[256];
    int t = threadIdx.x;
    int f = blockIdx.x * 256 + t;
    int v = (f < NSEG) ? cntd2[f] : 0;
    s[t] = v;
    __syncthreads();
    for (int off = 1; off < 256; off <<= 1) {
        int u = (t >= off) ? s[t - off] : 0;
        __syncthreads();
        s[t] += u;
        __syncthreads();
    }
    if (f < NSEG) {
        int ex = offs[blockIdx.x] + s[t] - v;
        rp2[f] = ex;
        if (f % (BKSZ * 4) == 0) gcur[f / (BKSZ * 4)] = ex;   // bucket base cursor
    }
    if (f == NSEG - 1) rp2[NSEG] = TE;
}

// Phase A: multi-split edges into 512 dst-range buckets.
// payload: src(16) | r(2 @16) | dlocal(7 @18)
__global__ __launch_bounds__(256) void k_fillA(const int* __restrict__ src,
                                               const int* __restrict__ dst,
                                               int* __restrict__ gcur,
                                               unsigned* __restrict__ stage) {
    __shared__ int cnt[NBK];
    __shared__ int rcur[NBK];
    int r = blockIdx.y;
    int base_e = blockIdx.x * CHA;
    int t = threadIdx.x;
    for (int i = t; i < NBK; i += 256) cnt[i] = 0;
    __syncthreads();
    const int* dr = dst + (size_t)r * EE;
    const int* sr = src + (size_t)r * EE;
    for (int i = base_e + t; i < base_e + CHA; i += 256) {
        int d = dr[i];
        atomicAdd(&cnt[d / BKSZ], 1);
    }
    __syncthreads();
    for (int i = t; i < NBK; i += 256) rcur[i] = (i * BKSZ < NN) ? atomicAdd(&gcur[i], cnt[i]) : 0;
    __syncthreads();
    for (int i = base_e + t; i < base_e + CHA; i += 256) {
        int d = dr[i];
        int s = sr[i];
        int b = d / BKSZ;
        int dl = d - b * BKSZ;
        int pos = atomicAdd(&rcur[b], 1);
        stage[pos] = (unsigned)s | ((unsigned)r << 16) | ((unsigned)dl << 18);
    }
}

// Phase B: one block per bucket; order into exact (d,r) segments via LDS image,
// emit 16B record {src, w0pk, w1pk, w2pk} with all 3 layers' bf16 weight pairs
// pre-folded (wLpk = bf16(cL0*ns*nd) | bf16(cL1*ns*nd)<<16).
__global__ __launch_bounds__(256) void k_fillB(const unsigned* __restrict__ stage,
                                               const int* __restrict__ rp2,
                                               const float* __restrict__ nsrc,
                                               const float* __restrict__ ndst,
                                               const float* __restrict__ c0p,
                                               const float* __restrict__ c1p,
                                               const float* __restrict__ c2p,
                                               uint4* __restrict__ ed) {
    __shared__ unsigned imgU[MAXSPAN];   // src | r<<16
    __shared__ float imgW[MAXSPAN];      // ns*nd
    __shared__ int lcur[BKSZ * 4];
    __shared__ float ndL[BKSZ * 4];
    int b = blockIdx.x;
    int t = threadIdx.x;
    int node0 = b * BKSZ;
    if (node0 >= NN) return;
    float c00 = c0p[0], c01 = c0p[1], c02 = c0p[2], c03 = c0p[3];
    float c04 = c0p[4], c05 = c0p[5], c06 = c0p[6], c07 = c0p[7];
    float c10 = c1p[0], c11 = c1p[1], c12 = c1p[2], c13 = c1p[3];
    float c14 = c1p[4], c15 = c1p[5], c16 = c1p[6], c17 = c1p[7];
    float c20 = c2p[0], c21 = c2p[1], c22 = c2p[2], c23 = c2p[3];
    float c24 = c2p[4], c25 = c2p[5], c26 = c2p[6], c27 = c2p[7];
    int nodes = min(BKSZ, NN - node0);
    int nseg_local = nodes * 4;
    int segbase = node0 * 4;
    for (int i = t; i < nseg_local; i += 256) {
        lcur[i] = rp2[segbase + i];
        ndL[i] = ndst[(i & 3) * NN + node0 + (i >> 2)];
    }
    __syncthreads();
    int S0 = rp2[segbase];
    int S1 = rp2[segbase + nseg_local];
    int span = S1 - S0;
    if (span <= MAXSPAN) {
        for (int i = S0 + t; i < S1; i += 256) {
            unsigned w = stage[i];
            int s = (int)(w & 0xFFFFu);
            int r = (int)((w >> 16) & 3u);
            int dl = (int)(w >> 18);
            int seg = dl * 4 + r;
            int pos = atomicAdd(&lcur[seg], 1);
            int idx = pos - S0;
            imgU[idx] = w & 0x3FFFFu;            // src | r<<16
            imgW[idx] = nsrc[r * NN + s] * ndL[seg];
        }
        __syncthreads();
        for (int i = t; i < span; i += 256) {
            unsigned u = imgU[i];
            float w = imgW[i];
            int r = (int)(u >> 16);
            float wa = (r == 0 ? c00 : r == 1 ? c02 : r == 2 ? c04 : c06) * w;
            float wb = (r == 0 ? c01 : r == 1 ? c03 : r == 2 ? c05 : c07) * w;
            float wc = (r == 0 ? c10 : r == 1 ? c12 : r == 2 ? c14 : c16) * w;
            float wd = (r == 0 ? c11 : r == 1 ? c13 : r == 2 ? c15 : c17) * w;
            float we = (r == 0 ? c20 : r == 1 ? c22 : r == 2 ? c24 : c26) * w;
            float wf = (r == 0 ? c21 : r == 1 ? c23 : r == 2 ? c25 : c27) * w;
            ed[S0 + i] = make_uint4(u & 0xFFFFu, pack2(wa, wb), pack2(wc, wd), pack2(we, wf));
        }
    } else {  // overflow fallback (statistically unreachable)
        for (int i = S0 + t; i < S1; i += 256) {
            unsigned w = stage[i];
            int s = (int)(w & 0xFFFFu);
            int r = (int)((w >> 16) & 3u);
            int dl = (int)(w >> 18);
            int seg = dl * 4 + r;
            int pos = atomicAdd(&lcur[seg], 1);
            float ww = nsrc[r * NN + s] * ndL[seg];
            float wa = (r == 0 ? c00 : r == 1 ? c02 : r == 2 ? c04 : c06) * ww;
            float wb = (r == 0 ? c01 : r == 1 ? c03 : r == 2 ? c05 : c07) * ww;
            float wc = (r == 0 ? c10 : r == 1 ? c12 : r == 2 ? c14 : c16) * ww;
            float wd = (r == 0 ? c11 : r == 1 ? c13 : r == 2 ? c15 : c17) * ww;
            float we = (r == 0 ? c20 : r == 1 ? c22 : r == 2 ? c24 : c26) * ww;
            float wf = (r == 0 ? c21 : r == 1 ? c23 : r == 2 ? c25 : c27) * ww;
            ed[pos] = make_uint4((unsigned)s, pack2(wa, wb), pack2(wc, wd), pack2(we, wf));
        }
    }
}

// ---------------- fused converts: x->bf16 + 3 basis transposes ----------------
__global__ __launch_bounds__(256) void k_cvt_all(const float4* __restrict__ x4,
                                                 const float* __restrict__ B0,
                                                 const float* __restrict__ B1,
                                                 const float* __restrict__ B2,
                                                 uint2* __restrict__ Xb,
                                                 unsigned short* __restrict__ Bt0,
                                                 unsigned short* __restrict__ Bt1,
                                                 unsigned short* __restrict__ Bt2) {
    int b = blockIdx.x;
    int t = threadIdx.x;
    if (b < XBLK) {
        int i = b * 256 + t;
        float4 v = x4[i];
        Xb[i] = make_uint2(pack2(v.x, v.y), pack2(v.z, v.w));
    } else if (b < XBLK + 128) {
        int o = (b - XBLK) * 256 + t;            // 32768 = 128*256
        int k = o & 255, n = o >> 8;
        Bt0[o] = f2bf(B0[k * 128 + n]);
    } else if (b < XBLK + 256) {
        int o = (b - XBLK - 128) * 256 + t;
        int k = o & 255, n = o >> 8;
        Bt1[o] = f2bf(B1[k * 128 + n]);
    } else {
        int o = (b - XBLK - 256) * 256 + t;      // 16384 = 64*256
        int k = o & 255, n = o >> 8;
        Bt2[o] = f2bf(B2[k * 64 + n]);
    }
}

// ---------------- aggregation: flat loop, quarter-wave/edge, 4 gathers in flight --
// ed: {src, w0pk, w1pk, w2pk}; layer's pack selected at compile time. NAMED
// SCALARS ONLY (vector/array locals spill to scratch: r8-r10, WRITE 392-598 MB).
template <int L>
__global__ __launch_bounds__(256) void k_agg(const uint4* __restrict__ hb4,
                                             const int* __restrict__ rp2,
                                             const uint4* __restrict__ ed,
                                             uint2* __restrict__ Mb2) {
    int wave = (blockIdx.x * 256 + threadIdx.x) >> 6;
    int lane = threadIdx.x & 63;
    if (wave >= NN) return;
    int q = lane >> 4, hl = lane & 15;

    float a00 = 0.f, a01 = 0.f, a02 = 0.f, a03 = 0.f;
    float a04 = 0.f, a05 = 0.f, a06 = 0.f, a07 = 0.f;
    float a10 = 0.f, a11 = 0.f, a12 = 0.f, a13 = 0.f;
    float a14 = 0.f, a15 = 0.f, a16 = 0.f, a17 = 0.f;

    int e0 = rp2[wave * 4], e1 = rp2[wave * 4 + 4];

    int e = e0;
    // main: 16 edges/iter, 4 per quarter, 4 gathers in flight
    for (; e + 15 < e1; e += 16) {
        uint4 pA = ed[e + q];
        uint4 pB = ed[e + 4 + q];
        uint4 pC = ed[e + 8 + q];
        uint4 pD = ed[e + 12 + q];
        uint4 hA = hb4[(size_t)pA.x * 16 + hl];
        uint4 hB = hb4[(size_t)pB.x * 16 + hl];
        uint4 hC = hb4[(size_t)pC.x * 16 + hl];
        uint4 hD = hb4[(size_t)pD.x * 16 + hl];
        unsigned kA = (L == 0) ? pA.y : (L == 1) ? pA.z : pA.w;
        unsigned kB = (L == 0) ? pB.y : (L == 1) ? pB.z : pB.w;
        unsigned kC = (L == 0) ? pC.y : (L == 1) ? pC.z : pC.w;
        unsigned kD = (L == 0) ? pD.y : (L == 1) ? pD.z : pD.w;
        float wA0 = blo(kA), wA1 = bhi(kA);
        float wB0 = blo(kB), wB1 = bhi(kB);
        float wC0 = blo(kC), wC1 = bhi(kC);
        float wD0 = blo(kD), wD1 = bhi(kD);

        float h0 = blo(hA.x), h1 = bhi(hA.x), h2 = blo(hA.y), h3 = bhi(hA.y);
        float h4 = blo(hA.z), h5 = bhi(hA.z), h6 = blo(hA.w), h7 = bhi(hA.w);
        a00 += wA0 * h0; a01 += wA0 * h1; a02 += wA0 * h2; a03 += wA0 * h3;
        a04 += wA0 * h4; a05 += wA0 * h5; a06 += wA0 * h6; a07 += wA0 * h7;
        a10 += wA1 * h0; a11 += wA1 * h1; a12 += wA1 * h2; a13 += wA1 * h3;
        a14 += wA1 * h4; a15 += wA1 * h5; a16 += wA1 * h6; a17 += wA1 * h7;

        h0 = blo(hB.x); h1 = bhi(hB.x); h2 = blo(hB.y); h3 = bhi(hB.y);
        h4 = blo(hB.z); h5 = bhi(hB.z); h6 = blo(hB.w); h7 = bhi(hB.w);
        a00 += wB0 * h0; a01 += wB0 * h1; a02 += wB0 * h2; a03 += wB0 * h3;
        a04 += wB0 * h4; a05 += wB0 * h5; a06 += wB0 * h6; a07 += wB0 * h7;
        a10 += wB1 * h0; a11 += wB1 * h1; a12 += wB1 * h2; a13 += wB1 * h3;
        a14 += wB1 * h4; a15 += wB1 * h5; a16 += wB1 * h6; a17 += wB1 * h7;

        h0 = blo(hC.x); h1 = bhi(hC.x); h2 = blo(hC.y); h3 = bhi(hC.y);
        h4 = blo(hC.z); h5 = bhi(hC.z); h6 = blo(hC.w); h7 = bhi(hC.w);
        a00 += wC0 * h0; a01 += wC0 * h1; a02 += wC0 * h2; a03 += wC0 * h3;
        a04 += wC0 * h4; a05 += wC0 * h5; a06 += wC0 * h6; a07 += wC0 * h7;
        a10 += wC1 * h0; a11 += wC1 * h1; a12 += wC1 * h2; a13 += wC1 * h3;
        a14 += wC1 * h4; a15 += wC1 * h5; a16 += wC1 * h6; a17 += wC1 * h7;

        h0 = blo(hD.x); h1 = bhi(hD.x); h2 = blo(hD.y); h3 = bhi(hD.y);
        h4 = blo(hD.z); h5 = bhi(hD.z); h6 = blo(hD.w); h7 = bhi(hD.w);
        a00 += wD0 * h0; a01 += wD0 * h1; a02 += wD0 * h2; a03 += wD0 * h3;
        a04 += wD0 * h4; a05 += wD0 * h5; a06 += wD0 * h6; a07 += wD0 * h7;
        a10 += wD1 * h0; a11 += wD1 * h1; a12 += wD1 * h2; a13 += wD1 * h3;
        a14 += wD1 * h4; a15 += wD1 * h5; a16 += wD1 * h6; a17 += wD1 * h7;
    }
    // masked tail: 4 edges/iter, one per quarter
    for (; e < e1; e += 4) {
        int E = e + q;
        bool act = E < e1;
        uint4 pA = ed[act ? E : e0];
        uint4 hA = hb4[(size_t)pA.x * 16 + hl];
        unsigned kA = (L == 0) ? pA.y : (L == 1) ? pA.z : pA.w;
        float wA0 = act ? blo(kA) : 0.f;
        float wA1 = act ? bhi(kA) : 0.f;
        float h0 = blo(hA.x), h1 = bhi(hA.x), h2 = blo(hA.y), h3 = bhi(hA.y);
        float h4 = blo(hA.z), h5 = bhi(hA.z), h6 = blo(hA.w), h7 = bhi(hA.w);
        a00 += wA0 * h0; a01 += wA0 * h1; a02 += wA0 * h2; a03 += wA0 * h3;
        a04 += wA0 * h4; a05 += wA0 * h5; a06 += wA0 * h6; a07 += wA0 * h7;
        a10 += wA1 * h0; a11 += wA1 * h1; a12 += wA1 * h2; a13 += wA1 * h3;
        a14 += wA1 * h4; a15 += wA1 * h5; a16 += wA1 * h6; a17 += wA1 * h7;
    }

    // cross-quarter reduce (xor 16, then 32)
    a00 += __shfl_xor(a00, 16, 64); a00 += __shfl_xor(a00, 32, 64);
    a01 += __shfl_xor(a01, 16, 64); a01 += __shfl_xor(a01, 32, 64);
    a02 += __shfl_xor(a02, 16, 64); a02 += __shfl_xor(a02, 32, 64);
    a03 += __shfl_xor(a03, 16, 64); a03 += __shfl_xor(a03, 32, 64);
    a04 += __shfl_xor(a04, 16, 64); a04 += __shfl_xor(a04, 32, 64);
    a05 += __shfl_xor(a05, 16, 64); a05 += __shfl_xor(a05, 32, 64);
    a06 += __shfl_xor(a06, 16, 64); a06 += __shfl_xor(a06, 32, 64);
    a07 += __shfl_xor(a07, 16, 64); a07 += __shfl_xor(a07, 32, 64);
    a10 += __shfl_xor(a10, 16, 64); a10 += __shfl_xor(a10, 32, 64);
    a11 += __shfl_xor(a11, 16, 64); a11 += __shfl_xor(a11, 32, 64);
    a12 += __shfl_xor(a12, 16, 64); a12 += __shfl_xor(a12, 32, 64);
    a13 += __shfl_xor(a13, 16, 64); a13 += __shfl_xor(a13, 32, 64);
    a14 += __shfl_xor(a14, 16, 64); a14 += __shfl_xor(a14, 32, 64);
    a15 += __shfl_xor(a15, 16, 64); a15 += __shfl_xor(a15, 32, 64);
    a16 += __shfl_xor(a16, 16, 64); a16 += __shfl_xor(a16, 32, 64);
    a17 += __shfl_xor(a17, 16, 64); a17 += __shfl_xor(a17, 32, 64);

    // lane (q,hl): coeff c = q>>1, half h4 = q&1 -> channels hl*8 + h4*4 + 0..3
    int c = q >> 1, h4 = q & 1;
    float v0 = c ? (h4 ? a14 : a10) : (h4 ? a04 : a00);
    float v1 = c ? (h4 ? a15 : a11) : (h4 ? a05 : a01);
    float v2 = c ? (h4 ? a16 : a12) : (h4 ? a06 : a02);
    float v3 = c ? (h4 ? a17 : a13) : (h4 ? a07 : a03);
    uint2 st;
    st.x = pack2(v0, v1);
    st.y = pack2(v2, v3);
    Mb2[(size_t)wave * 64 + c * 32 + hl * 2 + h4] = st;
}

// ---------------- MFMA bf16 GEMM: C[N,BN] = Mb[N,256] @ B[256,BN] ----------------
template <int BN, bool BF16OUT>
__global__ __launch_bounds__(256) void k_gemm(const unsigned short* __restrict__ A,
                                              const unsigned short* __restrict__ Bt,
                                              void* __restrict__ Cout) {
    int wave = threadIdx.x >> 6, lane = threadIdx.x & 63;
    int row0 = blockIdx.x * 64 + wave * 16;
    if (row0 >= NN) return;
    int m = lane & 15, q = lane >> 4;
    const int NT = BN / 16;

    frag_cd acc[NT];
#pragma unroll
    for (int ct = 0; ct < NT; ct++) acc[ct] = (frag_cd){0.f, 0.f, 0.f, 0.f};

    const size_t abase = (size_t)(row0 + m) * 256 + q * 8;
#pragma unroll
    for (int kc = 0; kc < 8; kc++) {
        frag_ab a = *(const frag_ab*)(A + abase + kc * 32);
#pragma unroll
        for (int ct = 0; ct < NT; ct++) {
            frag_ab b = *(const frag_ab*)(Bt + (size_t)(ct * 16 + m) * 256 + kc * 32 + q * 8);
            acc[ct] = __builtin_amdgcn_mfma_f32_16x16x32_bf16(a, b, acc[ct], 0, 0, 0);
        }
    }

#pragma unroll
    for (int ct = 0; ct < NT; ct++) {
#pragma unroll
        for (int i = 0; i < 4; i++) {
            int row = row0 + q * 4 + i;
            int col = ct * 16 + m;
            float v = acc[ct][i];
            if (BF16OUT) {
                v = fmaxf(v, 0.f);
                ((unsigned short*)Cout)[(size_t)row * BN + col] = f2bf(v);
            } else {
                ((float*)Cout)[(size_t)row * BN + col] = v;
            }
        }
    }
}

// ---------------- host ----------------

extern "C" void kernel_launch(void* const* d_in, const int* in_sizes, int n_in,
                              void* d_out, int out_size, void* d_ws, size_t ws_size,
                              hipStream_t stream) {
    const float* x      = (const float*)d_in[0];
    const int*   src    = (const int*)d_in[1];
    const int*   dst    = (const int*)d_in[2];
    const float* basis0 = (const float*)d_in[3];
    const float* coeff0 = (const float*)d_in[4];
    const float* basis1 = (const float*)d_in[5];
    const float* coeff1 = (const float*)d_in[6];
    const float* basis2 = (const float*)d_in[7];
    const float* coeff2 = (const float*)d_in[8];
    float* out = (float*)d_out;

    char* p = (char*)d_ws;
    auto alloc = [&](size_t bytes) {
        char* r = p;
        p += (bytes + 255) & ~(size_t)255;
        return r;
    };
    int*   cnt_srcQ = (int*)alloc((size_t)4 * RN * 4);
    int*   cnt_dstQ = (int*)alloc((size_t)4 * RN * 4);
    float* nsrc     = (float*)alloc((size_t)RN * 4);
    float* ndst     = (float*)alloc((size_t)RN * 4);
    int*   cntd2    = (int*)alloc((size_t)NSEG * 4);
    int*   rp2      = (int*)alloc((size_t)(NSEG + 1) * 4);
    int*   part     = (int*)alloc((size_t)SCB2 * 4);
    int*   offs     = (int*)alloc((size_t)SCB2 * 4);
    int*   gcur     = (int*)alloc((size_t)NBK * 4);
    unsigned* stage = (unsigned*)alloc((size_t)TE * 4);
    uint4* ed       = (uint4*)alloc((size_t)TE * 16);
    unsigned* Mb   = (unsigned*)alloc((size_t)NN * 128 * 4);        // bf16 [N][256]
    unsigned* Hb   = (unsigned*)alloc((size_t)NN * 64 * 4);         // bf16 [N][128]
    unsigned* Xb   = (unsigned*)alloc((size_t)NN * 64 * 4);         // bf16 [N][128]
    unsigned short* Bt0 = (unsigned short*)alloc((size_t)128 * 256 * 2);
    unsigned short* Bt1 = (unsigned short*)alloc((size_t)128 * 256 * 2);
    unsigned short* Bt2 = (unsigned short*)alloc((size_t)64 * 256 * 2);

    // setup
    k_cvt_all<<<XBLK + 320, 256, 0, stream>>>((const float4*)x, basis0, basis1, basis2,
                                              (uint2*)Xb, Bt0, Bt1, Bt2);
    k_hist<<<64, 1024, 0, stream>>>(src, dst, cnt_srcQ, cnt_dstQ);
    k_sum_norms<<<(RN + 255) / 256, 256, 0, stream>>>(cnt_srcQ, cnt_dstQ, nsrc, ndst, cntd2);
    k_partial<<<SCB2, 256, 0, stream>>>(cntd2, part);
    k_scan_small<<<1, 1024, 0, stream>>>(part, offs);
    k_emit<<<SCB2, 256, 0, stream>>>(cntd2, offs, rp2, gcur);
    k_fillA<<<dim3(EE / CHA, RR), 256, 0, stream>>>(src, dst, gcur, stage);
    k_fillB<<<NBK, 256, 0, stream>>>(stage, rp2, nsrc, ndst, coeff0, coeff1, coeff2, ed);

    int aggBlocks = NN / 4;
    int gemmBlocks = (NN + 63) / 64;   // 782

    // layer 0: Xb -> Mb -> Hb (relu, bf16)
    k_agg<0><<<aggBlocks, 256, 0, stream>>>((const uint4*)Xb, rp2, ed, (uint2*)Mb);
    k_gemm<128, true><<<gemmBlocks, 256, 0, stream>>>((const unsigned short*)Mb, Bt0, Hb);
    // layer 1
    k_agg<1><<<aggBlocks, 256, 0, stream>>>((const uint4*)Hb, rp2, ed, (uint2*)Mb);
    k_gemm<128, true><<<gemmBlocks, 256, 0, stream>>>((const unsigned short*)Mb, Bt1, Hb);
    // layer 2: final, fp32 out, no relu
    k_agg<2><<<aggBlocks, 256, 0, stream>>>((const uint4*)Hb, rp2, ed, (uint2*)Mb);
    k_gemm<64, false><<<gemmBlocks, 256, 0, stream>>>((const unsigned short*)Mb, Bt2, out);
}